// Round 10
// baseline (8090.595 us; speedup 1.0000x reference)
//
#include <hip/hip_runtime.h>
#include <hip/hip_bf16.h>
#include <cstdint>

typedef unsigned int u32;
typedef unsigned short u16;
typedef unsigned char u8;
typedef int i32x4 __attribute__((ext_vector_type(4)));
typedef u32 u32x4 __attribute__((ext_vector_type(4)));
typedef u32 u32x2 __attribute__((ext_vector_type(2)));
typedef float f32x4 __attribute__((ext_vector_type(4)));
typedef __bf16 bf16x8 __attribute__((ext_vector_type(8)));
typedef u16 u16x4 __attribute__((ext_vector_type(4)));

#define T_STEPS 512
#define NSLOT 16

// ---- workspace layout (bytes) ----
#define PROG_OFF 0u                      // 64 lines x 16 u32
#define G0_OFF   (64u * 1024u)
#define GRING_B  (NSLOT * 65536u * 4u)   // [16][4grp][512tid][32] u32 = 4 MB
#define G1_OFF   (G0_OFF + GRING_B)
#define HS0_OFF  (G1_OFF + GRING_B)
#define HS0_B    (NSLOT * 16384u * 4u)   // [16][64][256] u32 = 1 MB
#define WS_NEEDED (HS0_OFF + HS0_B)

#define P_REC0(g)   (g)
#define P_REC1(g)   (4 + (g))
#define P_PJ1(g, h) (8 + (g) * 2 + (h))

__device__ __forceinline__ float sigm(float z) { return 1.f / (1.f + __expf(-z)); }
__device__ __forceinline__ float tanh_(float z) { return 1.f - 2.f / (__expf(2.f * z) + 1.f); }
__device__ __forceinline__ u16 f2bf(float f) {
    union { __bf16 b; u16 u; } v; v.b = (__bf16)f; return v.u;
}
__device__ __forceinline__ float bf2f(u32 bits16) {
    union { u32 x; float f; } v; v.x = bits16 << 16; return v.f;
}
// Agent-scope relaxed atomics: MALL-coherent on any placement, no fences.
__device__ __forceinline__ u32 gload(const u32* p) {
    return __hip_atomic_load(p, __ATOMIC_RELAXED, __HIP_MEMORY_SCOPE_AGENT);
}
__device__ __forceinline__ void gstore(u32* p, u32 v) {
    __hip_atomic_store(p, v, __ATOMIC_RELAXED, __HIP_MEMORY_SCOPE_AGENT);
}

// ============================================================================
// Recurrence block: one per (layer, group). 512 threads = 8 waves.
// Owns ALL 1024 gate-rows x K=256 recurrent weights as int8 register fragments
// (per-row scales). h lives in LDS as dual-i8 (hi + lo/128); c in registers.
// Per step: NO cross-block dependency. G (x-projection + bias, from proj
// blocks) arrives via tagged ring, prefetched one full step ahead into regs.
// ============================================================================
template <bool IS_L0>
__device__ void rec_body(int grp, const float* __restrict__ W, u32* prog,
                         u32* __restrict__ Gring, u32* __restrict__ hs0,
                         float* __restrict__ out, char* smem)
{
    constexpr int KF = IS_L0 ? 384 : 512;   // W row stride (f32)
    constexpr float C1 = 1.f / 127.f;
    constexpr float C2 = 1.f / (127.f * 128.f);

    u8* hiB = (u8*)smem;                 // [2][16][272] = 8704 B
    u8* loB = (u8*)smem + 8704;          // [2][16][272]
    float* D = (float*)(smem + 17408);   // [16][1036] f32 = 66304 B

    const int tid = threadIdx.x;
    const int wave = tid >> 6;
    const int lane = tid & 63;
    const int mrow = lane & 15;          // MFMA row/col within tile
    const int kc = lane >> 4;            // k-chunk 0..3

    // ---- quantize W_h (cols 0..255) to i8 fragments + per-row scales ----
    i32x4 wq[8][4];
    float scl[8];
#pragma unroll
    for (int j = 0; j < 8; ++j) {
        const int row = wave * 128 + j * 16 + mrow;
        const float* Wr = W + (long)row * KF;
        float mx = 0.f;
#pragma unroll
        for (int kf = 0; kf < 4; ++kf) {
            const float* p = Wr + kf * 64 + kc * 16;
#pragma unroll
            for (int q = 0; q < 4; ++q) {
                float4 v = *(const float4*)(p + q * 4);
                mx = fmaxf(mx, fmaxf(fmaxf(fabsf(v.x), fabsf(v.y)),
                                     fmaxf(fabsf(v.z), fabsf(v.w))));
            }
        }
        mx = fmaxf(mx, __shfl_xor(mx, 16));
        mx = fmaxf(mx, __shfl_xor(mx, 32));
        const float inv = (mx > 0.f) ? 127.f / mx : 0.f;
        scl[j] = mx * C1;
#pragma unroll
        for (int kf = 0; kf < 4; ++kf) {
            const float* p = Wr + kf * 64 + kc * 16;
            int wds[4];
#pragma unroll
            for (int q = 0; q < 4; ++q) {
                float4 v = *(const float4*)(p + q * 4);
                int a = (int)rintf(v.x * inv), b = (int)rintf(v.y * inv);
                int c = (int)rintf(v.z * inv), d = (int)rintf(v.w * inv);
                wds[q] = (a & 255) | ((b & 255) << 8) | ((c & 255) << 16) | ((d & 255) << 24);
            }
            wq[j][kf] = (i32x4){wds[0], wds[1], wds[2], wds[3]};
        }
    }

    // zero h buffer 0 (h(0) = 0)
    for (int i = tid; i < 1088; i += 512) { ((u32*)hiB)[i] = 0; ((u32*)loB)[i] = 0; }

    // elementwise identity
    const int be = tid >> 5;             // batch 0..15
    const int d0 = (tid & 31) * 8;       // dims d0..d0+7
    float cst[8] = {0.f, 0.f, 0.f, 0.f, 0.f, 0.f, 0.f, 0.f};

    // G prefetch: this thread's 32 contiguous tagged words
    u32* gbase = Gring + grp * 16384 + tid * 32;
    u32 gw[32];
    {   // issue G(0) (tag 1, slot 0)
        const u32* gp = gbase;
#pragma unroll
        for (int i = 0; i < 32; ++i) gw[i] = gload(gp + i);
    }
    __syncthreads();

    for (int s = 0; s < T_STEPS; ++s) {
        const int cur = s & 1, nxt = cur ^ 1;

        // ---------- phase A: dual-i8 MFMA over K=256 ----------
        i32x4 acch[8], accl[8];
#pragma unroll
        for (int j = 0; j < 8; ++j) { acch[j] = (i32x4){0,0,0,0}; accl[j] = (i32x4){0,0,0,0}; }
#pragma unroll
        for (int kf = 0; kf < 4; ++kf) {
            i32x4 ah = *(const i32x4*)&hiB[cur * 4352 + mrow * 272 + kf * 64 + kc * 16];
            i32x4 al = *(const i32x4*)&loB[cur * 4352 + mrow * 272 + kf * 64 + kc * 16];
#pragma unroll
            for (int j = 0; j < 8; ++j) {
                acch[j] = __builtin_amdgcn_mfma_i32_16x16x64_i8(ah, wq[j][kf], acch[j], 0, 0, 0);
                accl[j] = __builtin_amdgcn_mfma_i32_16x16x64_i8(al, wq[j][kf], accl[j], 0, 0, 0);
            }
        }
        // dequant + write D[m][n]
#pragma unroll
        for (int j = 0; j < 8; ++j) {
            const int n = wave * 128 + j * 16 + mrow;
#pragma unroll
            for (int r = 0; r < 4; ++r) {
                float g = scl[j] * ((float)acch[j][r] * C1 + (float)accl[j][r] * C2);
                D[(kc * 4 + r) * 1036 + n] = g;
            }
        }
        __syncthreads();

        // ---------- phase B ----------
        // validate G(s) (tag s+1) — normally pre-arrived a full step ago
        {
            const u32 want = (u32)(s + 1);
            int gu = 0;
            for (;;) {
                u32 bad = 0;
#pragma unroll
                for (int i = 0; i < 32; ++i) bad |= (gw[i] >> 16) ^ want;
                if (!bad) break;
                if (++gu > (1 << 18)) break;
                const u32* rp = gbase + (size_t)(s & 15) * 65536;
#pragma unroll
                for (int i = 0; i < 32; ++i) gw[i] = gload(rp + i);
                if ((gu & 3) == 3) __builtin_amdgcn_s_sleep(1);
            }
        }
        // gather D rows for my 8 dims x 4 gates
        float dD[4][8];
#pragma unroll
        for (int g = 0; g < 4; ++g) {
            f32x4 a = *(const f32x4*)&D[be * 1036 + g * 256 + d0];
            f32x4 b = *(const f32x4*)&D[be * 1036 + g * 256 + d0 + 4];
#pragma unroll
            for (int q = 0; q < 4; ++q) { dD[g][q] = a[q]; dD[g][4 + q] = b[q]; }
        }
        float h8[8];
        u32 hw0 = 0, hw1 = 0, lw0 = 0, lw1 = 0;
#pragma unroll
        for (int jj = 0; jj < 8; ++jj) {
            const float zf = dD[0][jj] + bf2f(gw[0 * 8 + jj] & 0xffffu);
            const float zi = dD[1][jj] + bf2f(gw[1 * 8 + jj] & 0xffffu);
            const float zo = dD[2][jj] + bf2f(gw[2 * 8 + jj] & 0xffffu);
            const float zg = dD[3][jj] + bf2f(gw[3 * 8 + jj] & 0xffffu);
            const float f = sigm(zf), i_ = sigm(zi), o = sigm(zo), gt = tanh_(zg);
            const float cc = f * cst[jj] + i_ * gt;
            cst[jj] = cc;
            const float h = o * tanh_(cc);
            h8[jj] = h;
            // dual-i8 quantization: h = (hi + lo/128)/127
            const float t127 = h * 127.f;
            const float hif = rintf(t127);
            const float lof = rintf((t127 - hif) * 128.f);
            const int hii = (int)hif, loi = (int)lof;
            if (jj < 4) { hw0 |= (u32)(hii & 255) << (8 * jj);       lw0 |= (u32)(loi & 255) << (8 * jj); }
            else        { hw1 |= (u32)(hii & 255) << (8 * (jj - 4)); lw1 |= (u32)(loi & 255) << (8 * (jj - 4)); }
        }
        *(u32x2*)&hiB[nxt * 4352 + be * 272 + d0] = (u32x2){hw0, hw1};
        *(u32x2*)&loB[nxt * 4352 + be * 272 + d0] = (u32x2){lw0, lw1};

        if (IS_L0) {  // publish hs0(s) = h(s+1), tagged, fire-and-forget
            const u32 tg = (u32)(s + 1) << 16;
            u32* hp = hs0 + (size_t)((s + 1) & 15) * 16384 + (grp * 16 + be) * 256 + d0;
#pragma unroll
            for (int jj = 0; jj < 8; ++jj) gstore(hp + jj, tg | f2bf(h8[jj]));
        }

        if (s == T_STEPS - 1) {
            const int o1 = (grp * 16 + be) * 256 + d0;
#pragma unroll
            for (int jj = 0; jj < 8; ++jj) {
                if (IS_L0) {
                    out[16384 + o1 + jj] = h8[jj];   // h_n[0]
                    out[49152 + o1 + jj] = cst[jj];  // c_n[0]
                } else {
                    out[o1 + jj] = h8[jj];           // h1T
                    out[32768 + o1 + jj] = h8[jj];   // h_n[1]
                    out[65536 + o1 + jj] = cst[jj];  // c_n[1]
                }
            }
        }

        // issue G(s+1) loads (tag s+2) — land during next phase A
        if (s + 1 < T_STEPS) {
            const u32* np = gbase + (size_t)((s + 1) & 15) * 65536;
#pragma unroll
            for (int i = 0; i < 32; ++i) gw[i] = gload(np + i);
        }
        if (tid == 0)
            gstore(prog + (IS_L0 ? P_REC0(grp) : P_REC1(grp)) * 16, (u32)(s + 1));
        if (IS_L0) {  // hs0-ring overwrite protection: projL1 must keep up
            if ((s & 7) == 0 && s >= 8 && tid < 2) {
                const u32 need = (u32)(s - 4);
                const u32* pp = prog + P_PJ1(grp, tid) * 16;
                int gu = 0;
                while (gload(pp) < need && ++gu < (1 << 18)) {}
            }
        }
        __syncthreads();
    }
}

// ============================================================================
// proj-L0: one per group. G0(t) = x(t) @ W0x^T + b0 for all 1024 gates,
// 16 batches. Runs ahead of rec-L0; backpressure keeps lead <= ~13.
// ============================================================================
__device__ void proj0_body(int grp, const float* __restrict__ x,
                           const float* __restrict__ W, const float* __restrict__ bias,
                           u32* prog, u32* __restrict__ G0, char* smem)
{
    u16* A = (u16*)smem;   // [16][136] bf16
    const int tid = threadIdx.x, wave = tid >> 6, lane = tid & 63;
    const int mrow = lane & 15, kc = lane >> 4;

    bf16x8 wf[8][4];
    float bs[8];
#pragma unroll
    for (int j = 0; j < 8; ++j) {
        const int row = wave * 128 + j * 16 + mrow;
        const float* Wr = W + (long)row * 384 + 256;   // x-cols
#pragma unroll
        for (int kf = 0; kf < 4; ++kf) {
            const float* p = Wr + kf * 32 + kc * 8;
            float4 a = *(const float4*)p, b = *(const float4*)(p + 4);
            bf16x8 f;
            f[0]=(__bf16)a.x; f[1]=(__bf16)a.y; f[2]=(__bf16)a.z; f[3]=(__bf16)a.w;
            f[4]=(__bf16)b.x; f[5]=(__bf16)b.y; f[6]=(__bf16)b.z; f[7]=(__bf16)b.w;
            wf[j][kf] = f;
        }
        bs[j] = bias[row];
    }
    const int be = tid >> 5, d4 = (tid & 31) * 4;

    for (int t = 0; t < T_STEPS; ++t) {
        if ((t & 7) == 0 && t >= 8 && tid == 0) {   // G0-ring backpressure
            const u32 need = (u32)(t - 6);
            const u32* pp = prog + P_REC0(grp) * 16;
            int gu = 0;
            while (gload(pp) < need && ++gu < (1 << 18)) {}
        }
        {   // stage x(t) -> bf16 LDS
            const float* xp = x + ((long)(grp * 16 + be) * T_STEPS + t) * 128 + d4;
            float4 v = *(const float4*)xp;
            u16x4 h; h[0]=f2bf(v.x); h[1]=f2bf(v.y); h[2]=f2bf(v.z); h[3]=f2bf(v.w);
            *(u16x4*)&A[be * 136 + d4] = h;
        }
        __syncthreads();
        f32x4 acc[8];
#pragma unroll
        for (int j = 0; j < 8; ++j) acc[j] = (f32x4){bs[j], bs[j], bs[j], bs[j]};
#pragma unroll
        for (int kf = 0; kf < 4; ++kf) {
            bf16x8 af = *(const bf16x8*)&A[mrow * 136 + kf * 32 + kc * 8];
#pragma unroll
            for (int j = 0; j < 8; ++j)
                acc[j] = __builtin_amdgcn_mfma_f32_16x16x32_bf16(af, wf[j][kf], acc[j], 0, 0, 0);
        }
        // publish tagged into consumer-ordered ring
        const u32 tg = (u32)(t + 1) << 16;
        u32* base = G0 + (size_t)(t & 15) * 65536 + grp * 16384;
#pragma unroll
        for (int j = 0; j < 8; ++j) {
            const int n = wave * 128 + j * 16 + mrow;
            const int thi = (n & 255) >> 3;
            const int v0 = ((n >> 8) << 3) | (n & 7);
#pragma unroll
            for (int r = 0; r < 4; ++r) {
                const int m = kc * 4 + r;
                gstore(base + ((m << 5) | thi) * 32 + v0, tg | f2bf(acc[j][r]));
            }
        }
        __syncthreads();
    }
}

// ============================================================================
// proj-L1: two per group (gate-row halves). G1(t) = hs0(t) @ W1x^T + b1.
// Consumes tagged hs0 from rec-L0; throttled by rec-L1 progress.
// ============================================================================
__device__ void proj1_body(int grp, int half, const float* __restrict__ W,
                           const float* __restrict__ bias, u32* prog,
                           u32* __restrict__ G1, u32* __restrict__ hs0, char* smem)
{
    u16* A = (u16*)smem;   // [16][264] bf16
    const int tid = threadIdx.x, wave = tid >> 6, lane = tid & 63;
    const int mrow = lane & 15, kc = lane >> 4;

    bf16x8 wf[4][8];
    float bs[4];
#pragma unroll
    for (int j = 0; j < 4; ++j) {
        const int row = half * 512 + wave * 64 + j * 16 + mrow;
        const float* Wr = W + (long)row * 512 + 256;   // x-cols (= hs0)
#pragma unroll
        for (int kf = 0; kf < 8; ++kf) {
            const float* p = Wr + kf * 32 + kc * 8;
            float4 a = *(const float4*)p, b = *(const float4*)(p + 4);
            bf16x8 f;
            f[0]=(__bf16)a.x; f[1]=(__bf16)a.y; f[2]=(__bf16)a.z; f[3]=(__bf16)a.w;
            f[4]=(__bf16)b.x; f[5]=(__bf16)b.y; f[6]=(__bf16)b.z; f[7]=(__bf16)b.w;
            wf[j][kf] = f;
        }
        bs[j] = bias[row];
    }
    const int be = tid >> 5, d8 = (tid & 31) * 8;

    for (int t = 0; t < T_STEPS; ++t) {
        if ((t & 7) == 0 && t >= 8 && tid == 0) {   // G1-ring backpressure
            const u32 need = (u32)(t - 6);
            const u32* pp = prog + P_REC1(grp) * 16;
            int gu = 0;
            while (gload(pp) < need && ++gu < (1 << 18)) {}
        }
        {   // validated read of hs0(t) (tag t+1) -> bf16 LDS
            const u32 want = (u32)(t + 1);
            const u32* hp = hs0 + (size_t)((t + 1) & 15) * 16384 + (grp * 16 + be) * 256 + d8;
            u32 w[8];
            int gu = 0;
            for (;;) {
                u32 bad = 0;
#pragma unroll
                for (int i = 0; i < 8; ++i) w[i] = gload(hp + i);
#pragma unroll
                for (int i = 0; i < 8; ++i) bad |= (w[i] >> 16) ^ want;
                if (!bad) break;
                if (++gu > (1 << 18)) break;
                if ((gu & 3) == 3) __builtin_amdgcn_s_sleep(1);
            }
            u32x4 pk;
#pragma unroll
            for (int i = 0; i < 4; ++i) pk[i] = (w[2 * i] & 0xffffu) | (w[2 * i + 1] << 16);
            *(u32x4*)&A[be * 264 + d8] = pk;
        }
        __syncthreads();
        f32x4 acc[4];
#pragma unroll
        for (int j = 0; j < 4; ++j) acc[j] = (f32x4){bs[j], bs[j], bs[j], bs[j]};
#pragma unroll
        for (int kf = 0; kf < 8; ++kf) {
            bf16x8 af = *(const bf16x8*)&A[mrow * 264 + kf * 32 + kc * 8];
#pragma unroll
            for (int j = 0; j < 4; ++j)
                acc[j] = __builtin_amdgcn_mfma_f32_16x16x32_bf16(af, wf[j][kf], acc[j], 0, 0, 0);
        }
        const u32 tg = (u32)(t + 1) << 16;
        u32* base = G1 + (size_t)(t & 15) * 65536 + grp * 16384;
#pragma unroll
        for (int j = 0; j < 4; ++j) {
            const int n = half * 512 + wave * 64 + j * 16 + mrow;
            const int thi = (n & 255) >> 3;
            const int v0 = ((n >> 8) << 3) | (n & 7);
#pragma unroll
            for (int r = 0; r < 4; ++r) {
                const int m = kc * 4 + r;
                gstore(base + ((m << 5) | thi) * 32 + v0, tg | f2bf(acc[j][r]));
            }
        }
        if (tid == 0) gstore(prog + P_PJ1(grp, half) * 16, (u32)(t + 1));
        __syncthreads();
    }
}

__global__ __launch_bounds__(512, 2) void lstm_sys(
    const float* __restrict__ x,
    const float* __restrict__ W0, const float* __restrict__ b0,
    const float* __restrict__ W1, const float* __restrict__ b1,
    u32* prog, u32* G0, u32* G1, u32* hs0r,
    float* __restrict__ out)
{
    __shared__ __align__(16) char smem[83712];
    const int bid = blockIdx.x;
    if (bid < 8) {
        const int layer = bid >> 2, grp = bid & 3;
        if (layer == 0) rec_body<true >(grp, W0, prog, G0, hs0r, out, smem);
        else            rec_body<false>(grp, W1, prog, G1, hs0r, out, smem);
    } else if (bid < 12) {
        proj0_body(bid - 8, x, W0, b0, prog, G0, smem);
    } else {
        const int i = bid - 12;
        proj1_body(i >> 1, i & 1, W1, b1, prog, G1, hs0r, smem);
    }
}

extern "C" void kernel_launch(void* const* d_in, const int* in_sizes, int n_in,
                              void* d_out, int out_size, void* d_ws, size_t ws_size,
                              hipStream_t stream) {
    (void)in_sizes; (void)n_in; (void)out_size;
    const float* x  = (const float*)d_in[0];
    const float* W0 = (const float*)d_in[1];
    const float* b0 = (const float*)d_in[2];
    const float* W1 = (const float*)d_in[3];
    const float* b1 = (const float*)d_in[4];
    float* out = (float*)d_out;

    char* ws = (char*)d_ws;
    u32* prog = (u32*)(ws + PROG_OFF);
    u32* G0   = (u32*)(ws + G0_OFF);
    u32* G1   = (u32*)(ws + G1_OFF);
    u32* hs0r = (u32*)(ws + HS0_OFF);

    if (ws_size < WS_NEEDED) return;

    // Zero rings+prog each call: tag 0 != any wanted tag (>=1) and clears
    // stale tags from the previous replay. Replay-deterministic.
    hipMemsetAsync(d_ws, 0, WS_NEEDED, stream);

    lstm_sys<<<20, 512, 0, stream>>>(x, W0, b0, W1, b1, prog, G0, G1, hs0r, out);
}